// Round 1
// baseline (1413.222 us; speedup 1.0000x reference)
//
#include <hip/hip_runtime.h>
#include <math.h>

// Problem constants (reference: B=4, T=4096, D_MODEL=128, N_HEADS=4, HEAD_DIM=32)
#define B_   4
#define T_   4096
#define DM_  128
#define NH_  4
#define HD_  32
#define QKV_N 384            // 3 * DM_
#define TOKENS (B_ * T_)     // 16384
#define TENSOR_ELEMS (B_ * T_ * DM_)   // 2,097,152 elements per q/k/v tensor

// -------------------------------------------------------------------------
// Kernel 1: QKV projection.  C[m,n] = sum_k x[m,k] * Wqkv[n,k]
// m in [0,16384), n in [0,384). Scatter outputs to q/k/v laid out (B,H,T,32).
// Tile: 64 tokens x 64 cols per block, 256 threads, 4x4 microtile, K=128.
// -------------------------------------------------------------------------
__global__ __launch_bounds__(256) void qkv_proj_kernel(
    const float* __restrict__ x, const float* __restrict__ Wqkv,
    float* __restrict__ ws_qkv)
{
    __shared__ float xs[64 * 128];   // 32 KB
    __shared__ float wsh[64 * 128];  // 32 KB
    const int tid = threadIdx.x;
    const int m0 = blockIdx.x * 64;

    {   // stage x tile (64x128 floats = 2048 float4)
        const float4* xg = (const float4*)(x + (size_t)m0 * DM_);
        float4* xs4 = (float4*)xs;
        #pragma unroll
        for (int i = 0; i < 8; ++i) xs4[tid + 256 * i] = xg[tid + 256 * i];
    }

    const int tr = tid >> 4;   // 0..15 -> rows tr*4..+3
    const int tc = tid & 15;   // 0..15 -> cols tc*4..+3

    for (int ch = 0; ch < 6; ++ch) {
        __syncthreads();   // prior-iteration reads done (and xs stores visible on ch==0)
        {   // stage W chunk: rows ch*64 .. +64
            const float4* wg = (const float4*)(Wqkv + (size_t)ch * 64 * DM_);
            float4* ws4 = (float4*)wsh;
            #pragma unroll
            for (int i = 0; i < 8; ++i) ws4[tid + 256 * i] = wg[tid + 256 * i];
        }
        __syncthreads();

        float acc[4][4];
        #pragma unroll
        for (int i = 0; i < 4; ++i)
            #pragma unroll
            for (int j = 0; j < 4; ++j) acc[i][j] = 0.f;

        const float4* xs4 = (const float4*)xs;
        const float4* ws4 = (const float4*)wsh;
        #pragma unroll 4
        for (int k4 = 0; k4 < 32; ++k4) {
            float4 a[4], b[4];
            #pragma unroll
            for (int i = 0; i < 4; ++i) a[i] = xs4[(tr * 4 + i) * 32 + k4];
            #pragma unroll
            for (int j = 0; j < 4; ++j) b[j] = ws4[(tc * 4 + j) * 32 + k4];
            #pragma unroll
            for (int i = 0; i < 4; ++i)
                #pragma unroll
                for (int j = 0; j < 4; ++j)
                    acc[i][j] += a[i].x * b[j].x + a[i].y * b[j].y +
                                 a[i].z * b[j].z + a[i].w * b[j].w;
        }

        // scatter: n = ch*64 + tc*4 + j ; c=n>>7 (q/k/v), h=(n&127)>>5, d=n&31
        const int n_base = ch * 64 + tc * 4;     // 4-aligned, never crosses a 32-boundary
        const int cidx = n_base >> 7;
        const int h    = (n_base & 127) >> 5;
        const int d0   = n_base & 31;
        float* dst_base = ws_qkv + (size_t)cidx * TENSOR_ELEMS;
        #pragma unroll
        for (int i = 0; i < 4; ++i) {
            const int m = m0 + tr * 4 + i;
            const int b = m >> 12;          // m / 4096
            const int t = m & (T_ - 1);
            float* dst = dst_base + (((size_t)(b * NH_ + h) * T_ + t) * HD_ + d0);
            *(float4*)dst = make_float4(acc[i][0], acc[i][1], acc[i][2], acc[i][3]);
        }
    }
}

// -------------------------------------------------------------------------
// Kernel 2: causal flash attention, fp32.
// grid = (T/64, B*H); block = 64 threads (1 wave). Lane = one Q row.
// Q row in registers (pre-scaled), K/V 64x32 tiles staged in LDS,
// online softmax entirely per-lane (no cross-lane reductions).
// -------------------------------------------------------------------------
__global__ __launch_bounds__(64) void attn_kernel(
    const float* __restrict__ qg, const float* __restrict__ kg,
    const float* __restrict__ vg, float* __restrict__ og)
{
    __shared__ float ks[64 * HD_];   // 8 KB
    __shared__ float vs[64 * HD_];   // 8 KB

    const int tid = threadIdx.x;          // 0..63
    const int qt  = blockIdx.x;           // Q tile index, 0..63
    const int bh  = blockIdx.y;           // b*NH_ + h, 0..15
    const size_t base = (size_t)bh * T_ * HD_;
    const int r = qt * 64 + tid;          // global row (token index within (b,h))
    const float scale = 0.1767766952966369f;   // 1/sqrt(32)

    float q[HD_];
    {
        const float4* qrow = (const float4*)(qg + base + (size_t)r * HD_);
        #pragma unroll
        for (int i = 0; i < 8; ++i) {
            float4 t4 = qrow[i];
            q[4*i+0] = t4.x * scale; q[4*i+1] = t4.y * scale;
            q[4*i+2] = t4.z * scale; q[4*i+3] = t4.w * scale;
        }
    }

    float O[HD_];
    #pragma unroll
    for (int d = 0; d < HD_; ++d) O[d] = 0.f;
    float mrow = -INFINITY, l = 0.f;

    for (int kt = 0; kt <= qt; ++kt) {
        __syncthreads();   // previous iteration's LDS reads complete
        {   // stage K,V tile: 2048 floats each = 512 float4; 8 per lane
            const float4* kgt = (const float4*)(kg + base + (size_t)kt * 64 * HD_);
            const float4* vgt = (const float4*)(vg + base + (size_t)kt * 64 * HD_);
            float4* ks4 = (float4*)ks;
            float4* vs4 = (float4*)vs;
            #pragma unroll
            for (int i = 0; i < 8; ++i) {
                ks4[tid + 64 * i] = kgt[tid + 64 * i];
                vs4[tid + 64 * i] = vgt[tid + 64 * i];
            }
        }
        __syncthreads();

        float S[64];
        #pragma unroll
        for (int c = 0; c < 64; ++c) {
            const float4* kr = (const float4*)(ks + c * HD_);
            float acc = 0.f;
            #pragma unroll
            for (int i = 0; i < 8; ++i) {
                float4 kk = kr[i];
                acc += q[4*i+0]*kk.x + q[4*i+1]*kk.y + q[4*i+2]*kk.z + q[4*i+3]*kk.w;
            }
            S[c] = acc;
        }

        const bool diag = (kt == qt);
        float rmax = -INFINITY;
        #pragma unroll
        for (int c = 0; c < 64; ++c) {
            if (diag && c > tid) S[c] = -INFINITY;   // causal: col_global > row_global
            rmax = fmaxf(rmax, S[c]);
        }

        const float mnew = fmaxf(mrow, rmax);
        const float alpha = __expf(mrow - mnew);     // exp(-inf)=0 on first tile
        float psum = 0.f;
        #pragma unroll
        for (int c = 0; c < 64; ++c) {
            const float p = __expf(S[c] - mnew);
            S[c] = p;
            psum += p;
        }
        l = l * alpha + psum;
        #pragma unroll
        for (int d = 0; d < HD_; ++d) O[d] *= alpha;

        #pragma unroll
        for (int c = 0; c < 64; ++c) {
            const float pc = S[c];
            const float4* vr = (const float4*)(vs + c * HD_);
            #pragma unroll
            for (int i = 0; i < 8; ++i) {
                float4 vv = vr[i];
                O[4*i+0] += pc * vv.x; O[4*i+1] += pc * vv.y;
                O[4*i+2] += pc * vv.z; O[4*i+3] += pc * vv.w;
            }
        }
        mrow = mnew;
    }

    const float inv = 1.f / l;
    // write to attn_out laid out (B, T, H, D) == (B,T,128) row-major
    const int b = bh >> 2, h = bh & 3;
    float* orow = og + (((size_t)b * T_ + r) * NH_ + h) * HD_;
    #pragma unroll
    for (int i = 0; i < 8; ++i) {
        *(float4*)(orow + 4 * i) = make_float4(O[4*i+0]*inv, O[4*i+1]*inv,
                                               O[4*i+2]*inv, O[4*i+3]*inv);
    }
}

// -------------------------------------------------------------------------
// Kernel 3: output projection.  out[m,n] = sum_k attn[m,k] * Wout[n,k]
// Same tile structure as kernel 1; N=128 -> 2 chunks.
// -------------------------------------------------------------------------
__global__ __launch_bounds__(256) void out_proj_kernel(
    const float* __restrict__ a, const float* __restrict__ Wout,
    float* __restrict__ out)
{
    __shared__ float xs[64 * 128];
    __shared__ float wsh[64 * 128];
    const int tid = threadIdx.x;
    const int m0 = blockIdx.x * 64;

    {
        const float4* xg = (const float4*)(a + (size_t)m0 * DM_);
        float4* xs4 = (float4*)xs;
        #pragma unroll
        for (int i = 0; i < 8; ++i) xs4[tid + 256 * i] = xg[tid + 256 * i];
    }

    const int tr = tid >> 4;
    const int tc = tid & 15;

    for (int ch = 0; ch < 2; ++ch) {
        __syncthreads();
        {
            const float4* wg = (const float4*)(Wout + (size_t)ch * 64 * DM_);
            float4* ws4 = (float4*)wsh;
            #pragma unroll
            for (int i = 0; i < 8; ++i) ws4[tid + 256 * i] = wg[tid + 256 * i];
        }
        __syncthreads();

        float acc[4][4];
        #pragma unroll
        for (int i = 0; i < 4; ++i)
            #pragma unroll
            for (int j = 0; j < 4; ++j) acc[i][j] = 0.f;

        const float4* xs4 = (const float4*)xs;
        const float4* ws4 = (const float4*)wsh;
        #pragma unroll 4
        for (int k4 = 0; k4 < 32; ++k4) {
            float4 av[4], bv[4];
            #pragma unroll
            for (int i = 0; i < 4; ++i) av[i] = xs4[(tr * 4 + i) * 32 + k4];
            #pragma unroll
            for (int j = 0; j < 4; ++j) bv[j] = ws4[(tc * 4 + j) * 32 + k4];
            #pragma unroll
            for (int i = 0; i < 4; ++i)
                #pragma unroll
                for (int j = 0; j < 4; ++j)
                    acc[i][j] += av[i].x * bv[j].x + av[i].y * bv[j].y +
                                 av[i].z * bv[j].z + av[i].w * bv[j].w;
        }

        #pragma unroll
        for (int i = 0; i < 4; ++i) {
            const int m = m0 + tr * 4 + i;
            const int n = ch * 64 + tc * 4;
            *(float4*)(out + (size_t)m * DM_ + n) =
                make_float4(acc[i][0], acc[i][1], acc[i][2], acc[i][3]);
        }
    }
}

// -------------------------------------------------------------------------
extern "C" void kernel_launch(void* const* d_in, const int* in_sizes, int n_in,
                              void* d_out, int out_size, void* d_ws, size_t ws_size,
                              hipStream_t stream) {
    const float* x    = (const float*)d_in[0];   // (4,4096,128) fp32
    const float* Wqkv = (const float*)d_in[1];   // (384,128)    fp32
    const float* Wout = (const float*)d_in[2];   // (128,128)    fp32
    float* out = (float*)d_out;                  // (4,4096,128) fp32

    // workspace layout (floats): q | k | v | attn_out ; each TENSOR_ELEMS
    float* ws = (float*)d_ws;
    float* q_ws   = ws;
    float* k_ws   = ws + (size_t)TENSOR_ELEMS;
    float* v_ws   = ws + (size_t)2 * TENSOR_ELEMS;
    float* att_ws = ws + (size_t)3 * TENSOR_ELEMS;

    qkv_proj_kernel<<<TOKENS / 64, 256, 0, stream>>>(x, Wqkv, ws);
    attn_kernel<<<dim3(T_ / 64, B_ * NH_), 64, 0, stream>>>(q_ws, k_ws, v_ws, att_ws);
    out_proj_kernel<<<TOKENS / 64, 256, 0, stream>>>(att_ws, Wout, out);
}

// Round 2
// 970.481 us; speedup vs baseline: 1.4562x; 1.4562x over previous
//
#include <hip/hip_runtime.h>
#include <math.h>

// Problem constants (reference: B=4, T=4096, D_MODEL=128, N_HEADS=4, HEAD_DIM=32)
#define B_   4
#define T_   4096
#define DM_  128
#define NH_  4
#define HD_  32
#define TOKENS (B_ * T_)     // 16384
#define TENSOR_ELEMS (B_ * T_ * DM_)   // 2,097,152 elements per q/k/v tensor

// -------------------------------------------------------------------------
// Kernel 1: QKV projection.  C[m,n] = sum_k x[m,k] * Wqkv[n,k]
// m in [0,16384), n in [0,384). Scatter outputs to q/k/v laid out (B,H,T,32).
// -------------------------------------------------------------------------
__global__ __launch_bounds__(256) void qkv_proj_kernel(
    const float* __restrict__ x, const float* __restrict__ Wqkv,
    float* __restrict__ ws_qkv)
{
    __shared__ float xs[64 * 128];   // 32 KB
    __shared__ float wsh[64 * 128];  // 32 KB
    const int tid = threadIdx.x;
    const int m0 = blockIdx.x * 64;

    {   // stage x tile (64x128 floats = 2048 float4)
        const float4* xg = (const float4*)(x + (size_t)m0 * DM_);
        float4* xs4 = (float4*)xs;
        #pragma unroll
        for (int i = 0; i < 8; ++i) xs4[tid + 256 * i] = xg[tid + 256 * i];
    }

    const int tr = tid >> 4;   // 0..15 -> rows tr*4..+3
    const int tc = tid & 15;   // 0..15 -> cols tc*4..+3

    for (int ch = 0; ch < 6; ++ch) {
        __syncthreads();
        {   // stage W chunk: rows ch*64 .. +64
            const float4* wg = (const float4*)(Wqkv + (size_t)ch * 64 * DM_);
            float4* ws4 = (float4*)wsh;
            #pragma unroll
            for (int i = 0; i < 8; ++i) ws4[tid + 256 * i] = wg[tid + 256 * i];
        }
        __syncthreads();

        float acc[4][4];
        #pragma unroll
        for (int i = 0; i < 4; ++i)
            #pragma unroll
            for (int j = 0; j < 4; ++j) acc[i][j] = 0.f;

        const float4* xs4 = (const float4*)xs;
        const float4* ws4 = (const float4*)wsh;
        #pragma unroll 4
        for (int k4 = 0; k4 < 32; ++k4) {
            float4 a[4], b[4];
            #pragma unroll
            for (int i = 0; i < 4; ++i) a[i] = xs4[(tr * 4 + i) * 32 + k4];
            #pragma unroll
            for (int j = 0; j < 4; ++j) b[j] = ws4[(tc * 4 + j) * 32 + k4];
            #pragma unroll
            for (int i = 0; i < 4; ++i)
                #pragma unroll
                for (int j = 0; j < 4; ++j)
                    acc[i][j] += a[i].x * b[j].x + a[i].y * b[j].y +
                                 a[i].z * b[j].z + a[i].w * b[j].w;
        }

        const int n_base = ch * 64 + tc * 4;     // 4-aligned, never crosses a 32-boundary
        const int cidx = n_base >> 7;
        const int h    = (n_base & 127) >> 5;
        const int d0   = n_base & 31;
        float* dst_base = ws_qkv + (size_t)cidx * TENSOR_ELEMS;
        #pragma unroll
        for (int i = 0; i < 4; ++i) {
            const int m = m0 + tr * 4 + i;
            const int b = m >> 12;
            const int t = m & (T_ - 1);
            float* dst = dst_base + (((size_t)(b * NH_ + h) * T_ + t) * HD_ + d0);
            *(float4*)dst = make_float4(acc[i][0], acc[i][1], acc[i][2], acc[i][3]);
        }
    }
}

// -------------------------------------------------------------------------
// Kernel 2: causal flash attention, fp32, 4 waves/block.
// grid = (T/64, B*H); block = 256 (4 waves). Lane = one Q row (64 rows/block).
// Each wave handles KV tiles j = wave, wave+4, ... (32-row tiles), staging
// K/V into WAVE-PRIVATE LDS (no barriers in the main loop). Online-softmax
// partial states merged across waves at the end via LDS.
// -------------------------------------------------------------------------
__global__ __launch_bounds__(256, 4) void attn_kernel(
    const float* __restrict__ qg, const float* __restrict__ kg,
    const float* __restrict__ vg, float* __restrict__ og)
{
    __shared__ float smem[8192];     // 32 KB: staging (4 waves x 8 KB), reused for merge

    const int tid  = threadIdx.x;
    const int wave = tid >> 6;            // 0..3
    const int lane = tid & 63;            // 0..63
    const int qt   = blockIdx.x;          // Q tile index, 0..63
    const int bh   = blockIdx.y;          // b*NH_ + h, 0..15
    const size_t base = (size_t)bh * T_ * HD_;
    const int r = qt * 64 + lane;         // global Q row within (b,h)
    const float scale = 0.1767766952966369f;   // 1/sqrt(32)

    float q[HD_];
    {
        const float4* qrow = (const float4*)(qg + base + (size_t)r * HD_);
        #pragma unroll
        for (int i = 0; i < 8; ++i) {
            float4 t4 = qrow[i];
            q[4*i+0] = t4.x * scale; q[4*i+1] = t4.y * scale;
            q[4*i+2] = t4.z * scale; q[4*i+3] = t4.w * scale;
        }
    }

    float O[HD_];
    #pragma unroll
    for (int d = 0; d < HD_; ++d) O[d] = 0.f;
    float mrow = -INFINITY, l = 0.f;

    // wave-private staging: float4 view, 512 float4 per wave (K: 256, V: 256)
    float4* st4 = (float4*)smem + wave * 512;
    const int ntiles = 2 * qt + 2;        // 32-row KV tiles covering cols 0..qt*64+63

    for (int j = wave; j < ntiles; j += 4) {
        {   // stage K,V tile j (32x32 floats each = 256 float4; 4/lane each)
            const float4* kg4 = (const float4*)(kg + base + (size_t)j * 32 * HD_);
            const float4* vg4 = (const float4*)(vg + base + (size_t)j * 32 * HD_);
            #pragma unroll
            for (int i = 0; i < 4; ++i) {
                st4[lane + 64 * i]       = kg4[lane + 64 * i];
                st4[256 + lane + 64 * i] = vg4[lane + 64 * i];
            }
        }
        // wave-internal LDS visibility: compiler-inserted lgkmcnt, no barrier

        const int limit = r - j * 32;     // cols c > limit are masked (causal)
        float S[32];
        #pragma unroll
        for (int c = 0; c < 32; ++c) {
            const float4* kr = st4 + c * 8;
            float acc = 0.f;
            #pragma unroll
            for (int i = 0; i < 8; ++i) {
                float4 kk = kr[i];
                acc += q[4*i+0]*kk.x + q[4*i+1]*kk.y + q[4*i+2]*kk.z + q[4*i+3]*kk.w;
            }
            S[c] = (c <= limit) ? acc : -INFINITY;
        }

        float rmax = -INFINITY;
        #pragma unroll
        for (int c = 0; c < 32; ++c) rmax = fmaxf(rmax, S[c]);

        if (rmax > -INFINITY) {           // skip fully-masked tiles (avoids -inf - -inf NaN)
            const float mnew = fmaxf(mrow, rmax);
            const float alpha = __expf(mrow - mnew);   // exp(-inf)=0 on first live tile
            float psum = 0.f;
            #pragma unroll
            for (int c = 0; c < 32; ++c) {
                const float p = __expf(S[c] - mnew);
                S[c] = p;
                psum += p;
            }
            l = l * alpha + psum;
            #pragma unroll
            for (int d = 0; d < HD_; ++d) O[d] *= alpha;

            #pragma unroll
            for (int c = 0; c < 32; ++c) {
                const float pc = S[c];
                const float4* vr = st4 + 256 + c * 8;
                #pragma unroll
                for (int i = 0; i < 8; ++i) {
                    float4 vv = vr[i];
                    O[4*i+0] += pc * vv.x; O[4*i+1] += pc * vv.y;
                    O[4*i+2] += pc * vv.z; O[4*i+3] += pc * vv.w;
                }
            }
            mrow = mnew;
        }
    }

    // ---- merge partial states across the 4 waves ----
    __syncthreads();   // all waves done with staging reads; smem now reused
    // layout (floats): O_w (w=1..3) at (w-1)*2048 + d*64 + lane  (d-major, conflict-free)
    //                  m_w at 6144 + (w-1)*128 + lane ; l_w at +64
    if (wave > 0) {
        float* Obuf = smem + (wave - 1) * 2048;
        #pragma unroll
        for (int d = 0; d < HD_; ++d) Obuf[d * 64 + lane] = O[d];
        smem[6144 + (wave - 1) * 128 + lane]      = mrow;
        smem[6144 + (wave - 1) * 128 + 64 + lane] = l;
    }
    __syncthreads();

    if (wave == 0) {
        // wave 0 always processed tile j=0 (col 0 unmasked for every lane) -> mrow finite
        float mw[3], lw[3];
        #pragma unroll
        for (int w = 0; w < 3; ++w) {
            mw[w] = smem[6144 + w * 128 + lane];
            lw[w] = smem[6144 + w * 128 + 64 + lane];
        }
        float mstar = mrow;
        #pragma unroll
        for (int w = 0; w < 3; ++w) mstar = fmaxf(mstar, mw[w]);
        const float f0 = __expf(mrow - mstar);
        float lstar = l * f0;
        float fw[3];
        #pragma unroll
        for (int w = 0; w < 3; ++w) {
            fw[w] = __expf(mw[w] - mstar);    // exp(-inf - finite) = 0 for idle waves
            lstar += lw[w] * fw[w];
        }
        float Of[HD_];
        #pragma unroll
        for (int d = 0; d < HD_; ++d) {
            float acc = O[d] * f0;
            #pragma unroll
            for (int w = 0; w < 3; ++w)
                acc += fw[w] * smem[w * 2048 + d * 64 + lane];
            Of[d] = acc;
        }
        const float inv = 1.f / lstar;
        // write to attn_out laid out (B, T, H, D) == (B,T,128) row-major
        const int b = bh >> 2, h = bh & 3;
        float* orow = og + (((size_t)b * T_ + r) * NH_ + h) * HD_;
        #pragma unroll
        for (int i = 0; i < 8; ++i) {
            *(float4*)(orow + 4 * i) = make_float4(Of[4*i+0]*inv, Of[4*i+1]*inv,
                                                   Of[4*i+2]*inv, Of[4*i+3]*inv);
        }
    }
}

// -------------------------------------------------------------------------
// Kernel 3: output projection.  out[m,n] = sum_k attn[m,k] * Wout[n,k]
// -------------------------------------------------------------------------
__global__ __launch_bounds__(256) void out_proj_kernel(
    const float* __restrict__ a, const float* __restrict__ Wout,
    float* __restrict__ out)
{
    __shared__ float xs[64 * 128];
    __shared__ float wsh[64 * 128];
    const int tid = threadIdx.x;
    const int m0 = blockIdx.x * 64;

    {
        const float4* xg = (const float4*)(a + (size_t)m0 * DM_);
        float4* xs4 = (float4*)xs;
        #pragma unroll
        for (int i = 0; i < 8; ++i) xs4[tid + 256 * i] = xg[tid + 256 * i];
    }

    const int tr = tid >> 4;
    const int tc = tid & 15;

    for (int ch = 0; ch < 2; ++ch) {
        __syncthreads();
        {
            const float4* wg = (const float4*)(Wout + (size_t)ch * 64 * DM_);
            float4* ws4 = (float4*)wsh;
            #pragma unroll
            for (int i = 0; i < 8; ++i) ws4[tid + 256 * i] = wg[tid + 256 * i];
        }
        __syncthreads();

        float acc[4][4];
        #pragma unroll
        for (int i = 0; i < 4; ++i)
            #pragma unroll
            for (int j = 0; j < 4; ++j) acc[i][j] = 0.f;

        const float4* xs4 = (const float4*)xs;
        const float4* ws4 = (const float4*)wsh;
        #pragma unroll 4
        for (int k4 = 0; k4 < 32; ++k4) {
            float4 av[4], bv[4];
            #pragma unroll
            for (int i = 0; i < 4; ++i) av[i] = xs4[(tr * 4 + i) * 32 + k4];
            #pragma unroll
            for (int j = 0; j < 4; ++j) bv[j] = ws4[(tc * 4 + j) * 32 + k4];
            #pragma unroll
            for (int i = 0; i < 4; ++i)
                #pragma unroll
                for (int j = 0; j < 4; ++j)
                    acc[i][j] += av[i].x * bv[j].x + av[i].y * bv[j].y +
                                 av[i].z * bv[j].z + av[i].w * bv[j].w;
        }

        #pragma unroll
        for (int i = 0; i < 4; ++i) {
            const int m = m0 + tr * 4 + i;
            const int n = ch * 64 + tc * 4;
            *(float4*)(out + (size_t)m * DM_ + n) =
                make_float4(acc[i][0], acc[i][1], acc[i][2], acc[i][3]);
        }
    }
}

// -------------------------------------------------------------------------
extern "C" void kernel_launch(void* const* d_in, const int* in_sizes, int n_in,
                              void* d_out, int out_size, void* d_ws, size_t ws_size,
                              hipStream_t stream) {
    const float* x    = (const float*)d_in[0];   // (4,4096,128) fp32
    const float* Wqkv = (const float*)d_in[1];   // (384,128)    fp32
    const float* Wout = (const float*)d_in[2];   // (128,128)    fp32
    float* out = (float*)d_out;                  // (4,4096,128) fp32

    float* ws = (float*)d_ws;
    float* q_ws   = ws;
    float* k_ws   = ws + (size_t)TENSOR_ELEMS;
    float* v_ws   = ws + (size_t)2 * TENSOR_ELEMS;
    float* att_ws = ws + (size_t)3 * TENSOR_ELEMS;

    qkv_proj_kernel<<<TOKENS / 64, 256, 0, stream>>>(x, Wqkv, ws);
    attn_kernel<<<dim3(T_ / 64, B_ * NH_), 256, 0, stream>>>(q_ws, k_ws, v_ws, att_ws);
    out_proj_kernel<<<TOKENS / 64, 256, 0, stream>>>(att_ws, Wout, out);
}

// Round 3
// 302.313 us; speedup vs baseline: 4.6747x; 3.2102x over previous
//
#include <hip/hip_runtime.h>
#include <math.h>

// Problem constants (reference: B=4, T=4096, D_MODEL=128, N_HEADS=4, HEAD_DIM=32)
#define B_   4
#define T_   4096
#define DM_  128
#define NH_  4
#define HD_  32
#define TOKENS (B_ * T_)               // 16384
#define TENSOR_ELEMS (B_ * T_ * DM_)   // 2,097,152 elements (per full qkv component set)

typedef __attribute__((ext_vector_type(8))) short short8;   // 8 bf16 = 4 VGPRs (MFMA A/B frag)
typedef __attribute__((ext_vector_type(4))) float floatx4;  // MFMA C/D frag

__device__ __forceinline__ unsigned short f2bf(float f) {
    union { float f; unsigned int u; } v; v.f = f;
    unsigned int u = v.u;
    u += 0x7fffu + ((u >> 16) & 1u);   // round-to-nearest-even
    return (unsigned short)(u >> 16);
}

// -------------------------------------------------------------------------
// Kernel 1: QKV projection (fp32 compute).  C[m,n] = sum_k x[m,k]*Wqkv[n,k]
// Outputs: Q bf16 (bh,t,32) PRE-SCALED by 1/sqrt(32); K bf16 (bh,t,32);
//          V^T bf16 (bh,32,t)  [transposed for MFMA B-fragment reads]
// -------------------------------------------------------------------------
__global__ __launch_bounds__(256) void qkv_proj_kernel(
    const float* __restrict__ x, const float* __restrict__ Wqkv,
    unsigned short* __restrict__ q_bf, unsigned short* __restrict__ k_bf,
    unsigned short* __restrict__ v_t)
{
    __shared__ float xs[64 * 128];   // 32 KB
    __shared__ float wsh[64 * 128];  // 32 KB
    const int tid = threadIdx.x;
    const int m0 = blockIdx.x * 64;
    const float scale = 0.1767766952966369f;   // 1/sqrt(32)

    {   // stage x tile (64x128 floats = 2048 float4)
        const float4* xg = (const float4*)(x + (size_t)m0 * DM_);
        float4* xs4 = (float4*)xs;
        #pragma unroll
        for (int i = 0; i < 8; ++i) xs4[tid + 256 * i] = xg[tid + 256 * i];
    }

    const int tr = tid >> 4;   // 0..15 -> rows tr*4..+3
    const int tc = tid & 15;   // 0..15 -> cols tc*4..+3

    for (int ch = 0; ch < 6; ++ch) {
        __syncthreads();
        {   // stage W chunk: rows ch*64 .. +64
            const float4* wg = (const float4*)(Wqkv + (size_t)ch * 64 * DM_);
            float4* ws4 = (float4*)wsh;
            #pragma unroll
            for (int i = 0; i < 8; ++i) ws4[tid + 256 * i] = wg[tid + 256 * i];
        }
        __syncthreads();

        float acc[4][4];
        #pragma unroll
        for (int i = 0; i < 4; ++i)
            #pragma unroll
            for (int j = 0; j < 4; ++j) acc[i][j] = 0.f;

        const float4* xs4 = (const float4*)xs;
        const float4* ws4 = (const float4*)wsh;
        #pragma unroll 4
        for (int k4 = 0; k4 < 32; ++k4) {
            float4 a[4], b[4];
            #pragma unroll
            for (int i = 0; i < 4; ++i) a[i] = xs4[(tr * 4 + i) * 32 + k4];
            #pragma unroll
            for (int j = 0; j < 4; ++j) b[j] = ws4[(tc * 4 + j) * 32 + k4];
            #pragma unroll
            for (int i = 0; i < 4; ++i)
                #pragma unroll
                for (int j = 0; j < 4; ++j)
                    acc[i][j] += a[i].x * b[j].x + a[i].y * b[j].y +
                                 a[i].z * b[j].z + a[i].w * b[j].w;
        }

        // n = ch*64 + tc*4 + j ; cidx=n>>7 (0=q,1=k,2=v), h=(n&127)>>5, d0=n&31
        const int n_base = ch * 64 + tc * 4;     // 4-aligned, never crosses a 32-boundary
        const int cidx = n_base >> 7;
        const int h    = (n_base & 127) >> 5;
        const int d0   = n_base & 31;
        const int b    = m0 >> 12;
        const int t0   = (m0 & (T_ - 1)) + tr * 4;
        const int bh   = b * NH_ + h;

        if (cidx == 0) {         // Q: scale + bf16, layout (bh, t, 32)
            #pragma unroll
            for (int i = 0; i < 4; ++i) {
                ushort4 p;
                p.x = f2bf(acc[i][0] * scale); p.y = f2bf(acc[i][1] * scale);
                p.z = f2bf(acc[i][2] * scale); p.w = f2bf(acc[i][3] * scale);
                *(ushort4*)(q_bf + ((size_t)bh * T_ + (t0 + i)) * HD_ + d0) = p;
            }
        } else if (cidx == 1) {  // K: bf16, layout (bh, t, 32)
            #pragma unroll
            for (int i = 0; i < 4; ++i) {
                ushort4 p;
                p.x = f2bf(acc[i][0]); p.y = f2bf(acc[i][1]);
                p.z = f2bf(acc[i][2]); p.w = f2bf(acc[i][3]);
                *(ushort4*)(k_bf + ((size_t)bh * T_ + (t0 + i)) * HD_ + d0) = p;
            }
        } else {                 // V transposed: layout (bh, d, t)
            #pragma unroll
            for (int j = 0; j < 4; ++j) {
                ushort4 p;
                p.x = f2bf(acc[0][j]); p.y = f2bf(acc[1][j]);
                p.z = f2bf(acc[2][j]); p.w = f2bf(acc[3][j]);
                *(ushort4*)(v_t + ((size_t)bh * HD_ + (d0 + j)) * T_ + t0) = p;
            }
        }
    }
}

// -------------------------------------------------------------------------
// Kernel 2: bf16 MFMA causal flash attention.
// Block = 256 thr (4 waves), 64 Q rows (16/wave).  Bc = 64 K/V cols per tile.
// mfma_f32_16x16x32_bf16: A[m=lane&15][k=quad*8+j], B[n=lane&15][k=quad*8+j],
// C/D: col=lane&15, row=quad*4+reg  (HW-verified layouts, learn_hip m89/m91).
// K LDS rows padded to 80 B; V^T / P rows padded to 144 B (16B-aligned,
// <=2-way bank aliasing = free).  P C->A transform via LDS round-trip.
// -------------------------------------------------------------------------
__global__ __launch_bounds__(256, 4) void attn_mfma_kernel(
    const unsigned short* __restrict__ qb, const unsigned short* __restrict__ kb,
    const unsigned short* __restrict__ vtb, float* __restrict__ og)
{
    __shared__ __align__(16) char smem[5120 + 4608 + 4 * 2304];   // 18.5 KB
    char* kLds = smem;             // 64 rows x 80 B  (K tile, row-major (t,d))
    char* vLds = smem + 5120;      // 32 rows x 144 B (V^T tile, (d, t))
    const int tid  = threadIdx.x;
    const int wave = tid >> 6, lane = tid & 63;
    const int m    = lane & 15, q4 = lane >> 4;
    char* pLds = smem + 9728 + wave * 2304;   // per-wave 16 rows x 144 B

    // Dispatch swizzle: XCD-locality (2 heads per XCD) + per-CU qt balance.
    const int pid = blockIdx.x;
    const int xcd = pid & 7;
    const int r_  = pid >> 3;            // 0..127
    const int bh  = xcd * 2 + (r_ & 1);  // 0..15
    const int j_  = r_ >> 1;             // 0..63
    const int a_  = j_ & 15, k_ = j_ >> 4;
    const int qt  = (k_ == 0) ? a_ : (k_ == 1) ? 63 - a_
                  : (k_ == 2) ? 32 + a_ : 31 - a_;

    const size_t qkbase = (size_t)bh * T_ * HD_;   // in ushort elements
    const char* kg = (const char*)(kb + qkbase);
    const char* vg = (const char*)(vtb + qkbase);  // row d stride = T_*2 bytes

    // Q A-fragment straight from global: row qt*64+wave*16+m, bytes quad*16
    short8 qf = *(const short8*)((const char*)(qb + qkbase)
                 + (size_t)(qt * 64 + wave * 16 + m) * 64 + q4 * 16);

    floatx4 O0 = {0.f, 0.f, 0.f, 0.f}, O1 = {0.f, 0.f, 0.f, 0.f};
    float mx[4] = {-INFINITY, -INFINITY, -INFINITY, -INFINITY};
    float ls[4] = {0.f, 0.f, 0.f, 0.f};

    for (int kt = 0; kt <= qt; ++kt) {
        __syncthreads();   // prior-iteration LDS reads complete
        {   // stage K tile (64x64B) + V^T tile (32x128B), split over 256 thr
            const int krow = tid >> 2, ku = tid & 3;
            short8 kv = *(const short8*)(kg + (size_t)(kt * 64 + krow) * 64 + ku * 16);
            const int vd = tid >> 3, vu = tid & 7;
            short8 vv = *(const short8*)(vg + (size_t)vd * (T_ * 2)
                                            + (size_t)kt * 128 + vu * 16);
            *(short8*)(kLds + krow * 80 + ku * 16) = kv;
            *(short8*)(vLds + vd * 144 + vu * 16) = vv;
        }
        __syncthreads();

        // QK^T: 4 col-blocks, one MFMA each (K=32=head_dim)
        floatx4 s[4];
        #pragma unroll
        for (int nb = 0; nb < 4; ++nb) {
            short8 bfrag = *(const short8*)(kLds + (nb * 16 + m) * 80 + q4 * 16);
            floatx4 z = {0.f, 0.f, 0.f, 0.f};
            s[nb] = __builtin_amdgcn_mfma_f32_16x16x32_bf16(qf, bfrag, z, 0, 0, 0);
        }

        if (kt == qt) {   // causal mask on the diagonal tile
            #pragma unroll
            for (int nb = 0; nb < 4; ++nb)
                #pragma unroll
                for (int reg = 0; reg < 4; ++reg) {
                    const int col = nb * 16 + m;
                    const int row = wave * 16 + q4 * 4 + reg;
                    if (col > row) s[nb][reg] = -INFINITY;
                }
        }

        // online softmax; row = quad*4+reg, reduce over the 16 lanes of a quad
        float alpha[4], psum[4];
        #pragma unroll
        for (int reg = 0; reg < 4; ++reg) {
            float v = fmaxf(fmaxf(s[0][reg], s[1][reg]), fmaxf(s[2][reg], s[3][reg]));
            v = fmaxf(v, __shfl_xor(v, 1, 64));
            v = fmaxf(v, __shfl_xor(v, 2, 64));
            v = fmaxf(v, __shfl_xor(v, 4, 64));
            v = fmaxf(v, __shfl_xor(v, 8, 64));
            const float mn = fmaxf(mx[reg], v);
            alpha[reg] = __expf(mx[reg] - mn);   // exp(-inf)=0 on first tile
            mx[reg] = mn;
            psum[reg] = 0.f;
        }

        // exp, accumulate row-sums, scatter P (bf16) into wave-private LDS
        #pragma unroll
        for (int nb = 0; nb < 4; ++nb)
            #pragma unroll
            for (int reg = 0; reg < 4; ++reg) {
                const float p = __expf(s[nb][reg] - mx[reg]);
                psum[reg] += p;
                *(unsigned short*)(pLds + (q4 * 4 + reg) * 144 + (nb * 16 + m) * 2) = f2bf(p);
            }

        #pragma unroll
        for (int reg = 0; reg < 4; ++reg) {
            float v = psum[reg];
            v += __shfl_xor(v, 1, 64);
            v += __shfl_xor(v, 2, 64);
            v += __shfl_xor(v, 4, 64);
            v += __shfl_xor(v, 8, 64);
            ls[reg] = ls[reg] * alpha[reg] + v;
            O0[reg] *= alpha[reg];
            O1[reg] *= alpha[reg];
        }

        // drain P writes before cross-lane A-fragment reads (wave-internal)
        __asm__ volatile("s_waitcnt lgkmcnt(0)" ::: "memory");

        // PV: A = P (16x64), B = V^T frags; accumulate O (16x32) in 2 C-frags
        short8 a0  = *(const short8*)(pLds + m * 144 + q4 * 16);        // k 0..31
        short8 a1  = *(const short8*)(pLds + m * 144 + 64 + q4 * 16);   // k 32..63
        short8 v00 = *(const short8*)(vLds + m * 144 + q4 * 16);            // d0..15, k 0..31
        short8 v10 = *(const short8*)(vLds + m * 144 + 64 + q4 * 16);       // d0..15, k 32..63
        short8 v01 = *(const short8*)(vLds + (16 + m) * 144 + q4 * 16);     // d16..31, k 0..31
        short8 v11 = *(const short8*)(vLds + (16 + m) * 144 + 64 + q4 * 16);// d16..31, k 32..63
        O0 = __builtin_amdgcn_mfma_f32_16x16x32_bf16(a0, v00, O0, 0, 0, 0);
        O0 = __builtin_amdgcn_mfma_f32_16x16x32_bf16(a1, v10, O0, 0, 0, 0);
        O1 = __builtin_amdgcn_mfma_f32_16x16x32_bf16(a0, v01, O1, 0, 0, 0);
        O1 = __builtin_amdgcn_mfma_f32_16x16x32_bf16(a1, v11, O1, 0, 0, 0);
    }

    // epilogue: normalize, write fp32 attn_out laid out (B, T, H, D)
    const int b = bh >> 2, h = bh & 3;
    #pragma unroll
    for (int reg = 0; reg < 4; ++reg) {
        const float inv = 1.f / ls[reg];
        const int t = qt * 64 + wave * 16 + q4 * 4 + reg;
        float* orow = og + (((size_t)b * T_ + t) * NH_ + h) * HD_;
        orow[m]      = O0[reg] * inv;
        orow[16 + m] = O1[reg] * inv;
    }
}

// -------------------------------------------------------------------------
// Kernel 3: output projection (fp32).  out[m,n] = sum_k attn[m,k]*Wout[n,k]
// -------------------------------------------------------------------------
__global__ __launch_bounds__(256) void out_proj_kernel(
    const float* __restrict__ a, const float* __restrict__ Wout,
    float* __restrict__ out)
{
    __shared__ float xs[64 * 128];
    __shared__ float wsh[64 * 128];
    const int tid = threadIdx.x;
    const int m0 = blockIdx.x * 64;

    {
        const float4* xg = (const float4*)(a + (size_t)m0 * DM_);
        float4* xs4 = (float4*)xs;
        #pragma unroll
        for (int i = 0; i < 8; ++i) xs4[tid + 256 * i] = xg[tid + 256 * i];
    }

    const int tr = tid >> 4;
    const int tc = tid & 15;

    for (int ch = 0; ch < 2; ++ch) {
        __syncthreads();
        {
            const float4* wg = (const float4*)(Wout + (size_t)ch * 64 * DM_);
            float4* ws4 = (float4*)wsh;
            #pragma unroll
            for (int i = 0; i < 8; ++i) ws4[tid + 256 * i] = wg[tid + 256 * i];
        }
        __syncthreads();

        float acc[4][4];
        #pragma unroll
        for (int i = 0; i < 4; ++i)
            #pragma unroll
            for (int j = 0; j < 4; ++j) acc[i][j] = 0.f;

        const float4* xs4 = (const float4*)xs;
        const float4* ws4 = (const float4*)wsh;
        #pragma unroll 4
        for (int k4 = 0; k4 < 32; ++k4) {
            float4 av[4], bv[4];
            #pragma unroll
            for (int i = 0; i < 4; ++i) av[i] = xs4[(tr * 4 + i) * 32 + k4];
            #pragma unroll
            for (int j = 0; j < 4; ++j) bv[j] = ws4[(tc * 4 + j) * 32 + k4];
            #pragma unroll
            for (int i = 0; i < 4; ++i)
                #pragma unroll
                for (int j = 0; j < 4; ++j)
                    acc[i][j] += av[i].x * bv[j].x + av[i].y * bv[j].y +
                                 av[i].z * bv[j].z + av[i].w * bv[j].w;
        }

        #pragma unroll
        for (int i = 0; i < 4; ++i) {
            const int mm = m0 + tr * 4 + i;
            const int n = ch * 64 + tc * 4;
            *(float4*)(out + (size_t)mm * DM_ + n) =
                make_float4(acc[i][0], acc[i][1], acc[i][2], acc[i][3]);
        }
    }
}

// -------------------------------------------------------------------------
extern "C" void kernel_launch(void* const* d_in, const int* in_sizes, int n_in,
                              void* d_out, int out_size, void* d_ws, size_t ws_size,
                              hipStream_t stream) {
    const float* x    = (const float*)d_in[0];   // (4,4096,128) fp32
    const float* Wqkv = (const float*)d_in[1];   // (384,128)    fp32
    const float* Wout = (const float*)d_in[2];   // (128,128)    fp32
    float* out = (float*)d_out;                  // (4,4096,128) fp32

    // ws layout (bytes): q_bf 4MB | k_bf 4MB | v_t 4MB | att_ws fp32 8MB
    char* ws = (char*)d_ws;
    unsigned short* q_bf  = (unsigned short*)(ws);
    unsigned short* k_bf  = (unsigned short*)(ws + (size_t)4 * 1024 * 1024);
    unsigned short* v_t   = (unsigned short*)(ws + (size_t)8 * 1024 * 1024);
    float*          att_ws = (float*)(ws + (size_t)12 * 1024 * 1024);

    qkv_proj_kernel<<<TOKENS / 64, 256, 0, stream>>>(x, Wqkv, q_bf, k_bf, v_t);
    attn_mfma_kernel<<<1024, 256, 0, stream>>>(q_bf, k_bf, v_t, att_ws);
    out_proj_kernel<<<TOKENS / 64, 256, 0, stream>>>(att_ws, Wout, out);
}

// Round 4
// 187.441 us; speedup vs baseline: 7.5395x; 1.6128x over previous
//
#include <hip/hip_runtime.h>
#include <math.h>

// Problem constants (reference: B=4, T=4096, D_MODEL=128, N_HEADS=4, HEAD_DIM=32)
#define B_   4
#define T_   4096
#define DM_  128
#define NH_  4
#define HD_  32
#define TOKENS (B_ * T_)               // 16384

typedef __attribute__((ext_vector_type(8))) short short8;   // 8 bf16 = 4 VGPRs (MFMA A/B frag)
typedef __attribute__((ext_vector_type(4))) float floatx4;  // MFMA C/D frag

__device__ __forceinline__ unsigned short f2bf(float f) {
    union { float f; unsigned int u; } v; v.f = f;
    unsigned int u = v.u;
    u += 0x7fffu + ((u >> 16) & 1u);   // round-to-nearest-even
    return (unsigned short)(u >> 16);
}
__device__ __forceinline__ void split_bf(float v, unsigned short& hi, unsigned short& lo) {
    unsigned short h = f2bf(v);
    float hf = __uint_as_float(((unsigned int)h) << 16);
    hi = h;
    lo = f2bf(v - hf);
}

// LDS row stride for bf16 tiles: 128 elements + 8 pad = 136 shorts = 272 B.
// 272 B = 17*16: b128-aligned; bank advance 4 dwords/row -> <=2-way aliasing (free).
#define LROW 136

// -------------------------------------------------------------------------
// Kernel 1: QKV projection via MFMA, hi/lo bf16 split (fp32-grade accuracy).
// C[m,n] = sum_k x[m,k] * Wqkv[n,k];  M=16384 (64/block), N=384 (6 chunks of 64).
// Outputs: Q bf16 (bh,t,32) PRE-SCALED by 1/sqrt(32); K bf16 (bh,t,32);
//          V^T bf16 (bh,32,t).
// -------------------------------------------------------------------------
__global__ __launch_bounds__(256) void qkv_proj_kernel(
    const float* __restrict__ x, const float* __restrict__ Wqkv,
    unsigned short* __restrict__ q_bf, unsigned short* __restrict__ k_bf,
    unsigned short* __restrict__ v_t)
{
    __shared__ __align__(16) unsigned short lds[4 * 64 * LROW];   // 68 KB
    unsigned short* xhi = lds;
    unsigned short* xlo = lds + 64 * LROW;
    unsigned short* whi = lds + 2 * 64 * LROW;
    unsigned short* wlo = lds + 3 * 64 * LROW;

    const int tid  = threadIdx.x;
    const int wave = tid >> 6, lane = tid & 63;
    const int m    = lane & 15, q4 = lane >> 4;
    const int m0   = blockIdx.x * 64;
    const float scale = 0.1767766952966369f;   // 1/sqrt(32)

    {   // stage x tile 64x128 fp32 -> hi/lo bf16 LDS
        const float4* xg = (const float4*)(x + (size_t)m0 * DM_);
        #pragma unroll
        for (int i = 0; i < 8; ++i) {
            const int f = tid + 256 * i;
            float4 v = xg[f];
            const int row = f >> 5, k4 = f & 31;
            ushort4 h, l;
            split_bf(v.x, h.x, l.x); split_bf(v.y, h.y, l.y);
            split_bf(v.z, h.z, l.z); split_bf(v.w, h.w, l.w);
            *(ushort4*)(xhi + row * LROW + k4 * 4) = h;
            *(ushort4*)(xlo + row * LROW + k4 * 4) = l;
        }
    }
    __syncthreads();

    // A fragments (rows wave*16 + m), hoisted: 4 k-steps x {hi,lo}
    short8 Ah[4], Al[4];
    #pragma unroll
    for (int ks = 0; ks < 4; ++ks) {
        Ah[ks] = *(const short8*)(xhi + (wave * 16 + m) * LROW + ks * 32 + q4 * 8);
        Al[ks] = *(const short8*)(xlo + (wave * 16 + m) * LROW + ks * 32 + q4 * 8);
    }

    for (int ch = 0; ch < 6; ++ch) {
        // prefetch W chunk (rows ch*64..+64) into registers
        float4 wreg[8];
        {
            const float4* wg = (const float4*)(Wqkv + (size_t)ch * 64 * DM_);
            #pragma unroll
            for (int i = 0; i < 8; ++i) wreg[i] = wg[tid + 256 * i];
        }
        __syncthreads();   // previous chunk's B-frag reads complete
        #pragma unroll
        for (int i = 0; i < 8; ++i) {
            const int f = tid + 256 * i;
            const int row = f >> 5, k4 = f & 31;
            ushort4 h, l;
            split_bf(wreg[i].x, h.x, l.x); split_bf(wreg[i].y, h.y, l.y);
            split_bf(wreg[i].z, h.z, l.z); split_bf(wreg[i].w, h.w, l.w);
            *(ushort4*)(whi + row * LROW + k4 * 4) = h;
            *(ushort4*)(wlo + row * LROW + k4 * 4) = l;
        }
        __syncthreads();

        #pragma unroll
        for (int nb = 0; nb < 4; ++nb) {
            floatx4 acc = {0.f, 0.f, 0.f, 0.f};
            #pragma unroll
            for (int ks = 0; ks < 4; ++ks) {
                short8 Bh = *(const short8*)(whi + (nb * 16 + m) * LROW + ks * 32 + q4 * 8);
                short8 Bl = *(const short8*)(wlo + (nb * 16 + m) * LROW + ks * 32 + q4 * 8);
                acc = __builtin_amdgcn_mfma_f32_16x16x32_bf16(Ah[ks], Bh, acc, 0, 0, 0);
                acc = __builtin_amdgcn_mfma_f32_16x16x32_bf16(Ah[ks], Bl, acc, 0, 0, 0);
                acc = __builtin_amdgcn_mfma_f32_16x16x32_bf16(Al[ks], Bh, acc, 0, 0, 0);
            }
            // epilogue: n = ch*64 + nb*16 + m ; cidx=n>>7, h=(n>>5)&3, d=n&31
            const int n    = ch * 64 + nb * 16 + m;
            const int cidx = n >> 7;
            const int hh   = (n >> 5) & 3;
            const int d    = n & 31;
            #pragma unroll
            for (int reg = 0; reg < 4; ++reg) {
                const int token = m0 + wave * 16 + q4 * 4 + reg;
                const int b = token >> 12, t = token & (T_ - 1);
                const int bh = b * NH_ + hh;
                if (cidx == 0) {
                    q_bf[((size_t)bh * T_ + t) * HD_ + d] = f2bf(acc[reg] * scale);
                } else if (cidx == 1) {
                    k_bf[((size_t)bh * T_ + t) * HD_ + d] = f2bf(acc[reg]);
                } else {
                    v_t[((size_t)bh * HD_ + d) * T_ + t] = f2bf(acc[reg]);
                }
            }
        }
    }
}

// -------------------------------------------------------------------------
// Kernel 2: bf16 MFMA causal flash attention (unchanged from R3).
// Block = 256 thr (4 waves), 64 Q rows (16/wave).  Bc = 64 K/V cols per tile.
// -------------------------------------------------------------------------
__global__ __launch_bounds__(256, 4) void attn_mfma_kernel(
    const unsigned short* __restrict__ qb, const unsigned short* __restrict__ kb,
    const unsigned short* __restrict__ vtb, float* __restrict__ og)
{
    __shared__ __align__(16) char smem[5120 + 4608 + 4 * 2304];   // 18.5 KB
    char* kLds = smem;             // 64 rows x 80 B  (K tile, row-major (t,d))
    char* vLds = smem + 5120;      // 32 rows x 144 B (V^T tile, (d, t))
    const int tid  = threadIdx.x;
    const int wave = tid >> 6, lane = tid & 63;
    const int m    = lane & 15, q4 = lane >> 4;
    char* pLds = smem + 9728 + wave * 2304;   // per-wave 16 rows x 144 B

    // Dispatch swizzle: XCD-locality (2 heads per XCD) + per-CU qt balance.
    const int pid = blockIdx.x;
    const int xcd = pid & 7;
    const int r_  = pid >> 3;            // 0..127
    const int bh  = xcd * 2 + (r_ & 1);  // 0..15
    const int j_  = r_ >> 1;             // 0..63
    const int a_  = j_ & 15, k_ = j_ >> 4;
    const int qt  = (k_ == 0) ? a_ : (k_ == 1) ? 63 - a_
                  : (k_ == 2) ? 32 + a_ : 31 - a_;

    const size_t qkbase = (size_t)bh * T_ * HD_;   // in ushort elements
    const char* kg = (const char*)(kb + qkbase);
    const char* vg = (const char*)(vtb + qkbase);  // row d stride = T_*2 bytes

    short8 qf = *(const short8*)((const char*)(qb + qkbase)
                 + (size_t)(qt * 64 + wave * 16 + m) * 64 + q4 * 16);

    floatx4 O0 = {0.f, 0.f, 0.f, 0.f}, O1 = {0.f, 0.f, 0.f, 0.f};
    float mx[4] = {-INFINITY, -INFINITY, -INFINITY, -INFINITY};
    float ls[4] = {0.f, 0.f, 0.f, 0.f};

    for (int kt = 0; kt <= qt; ++kt) {
        __syncthreads();
        {   // stage K tile (64x64B) + V^T tile (32x128B), split over 256 thr
            const int krow = tid >> 2, ku = tid & 3;
            short8 kv = *(const short8*)(kg + (size_t)(kt * 64 + krow) * 64 + ku * 16);
            const int vd = tid >> 3, vu = tid & 7;
            short8 vv = *(const short8*)(vg + (size_t)vd * (T_ * 2)
                                            + (size_t)kt * 128 + vu * 16);
            *(short8*)(kLds + krow * 80 + ku * 16) = kv;
            *(short8*)(vLds + vd * 144 + vu * 16) = vv;
        }
        __syncthreads();

        floatx4 s[4];
        #pragma unroll
        for (int nb = 0; nb < 4; ++nb) {
            short8 bfrag = *(const short8*)(kLds + (nb * 16 + m) * 80 + q4 * 16);
            floatx4 z = {0.f, 0.f, 0.f, 0.f};
            s[nb] = __builtin_amdgcn_mfma_f32_16x16x32_bf16(qf, bfrag, z, 0, 0, 0);
        }

        if (kt == qt) {
            #pragma unroll
            for (int nb = 0; nb < 4; ++nb)
                #pragma unroll
                for (int reg = 0; reg < 4; ++reg) {
                    const int col = nb * 16 + m;
                    const int row = wave * 16 + q4 * 4 + reg;
                    if (col > row) s[nb][reg] = -INFINITY;
                }
        }

        float alpha[4], psum[4];
        #pragma unroll
        for (int reg = 0; reg < 4; ++reg) {
            float v = fmaxf(fmaxf(s[0][reg], s[1][reg]), fmaxf(s[2][reg], s[3][reg]));
            v = fmaxf(v, __shfl_xor(v, 1, 64));
            v = fmaxf(v, __shfl_xor(v, 2, 64));
            v = fmaxf(v, __shfl_xor(v, 4, 64));
            v = fmaxf(v, __shfl_xor(v, 8, 64));
            const float mn = fmaxf(mx[reg], v);
            alpha[reg] = __expf(mx[reg] - mn);
            mx[reg] = mn;
            psum[reg] = 0.f;
        }

        #pragma unroll
        for (int nb = 0; nb < 4; ++nb)
            #pragma unroll
            for (int reg = 0; reg < 4; ++reg) {
                const float p = __expf(s[nb][reg] - mx[reg]);
                psum[reg] += p;
                *(unsigned short*)(pLds + (q4 * 4 + reg) * 144 + (nb * 16 + m) * 2) = f2bf(p);
            }

        #pragma unroll
        for (int reg = 0; reg < 4; ++reg) {
            float v = psum[reg];
            v += __shfl_xor(v, 1, 64);
            v += __shfl_xor(v, 2, 64);
            v += __shfl_xor(v, 4, 64);
            v += __shfl_xor(v, 8, 64);
            ls[reg] = ls[reg] * alpha[reg] + v;
            O0[reg] *= alpha[reg];
            O1[reg] *= alpha[reg];
        }

        __asm__ volatile("s_waitcnt lgkmcnt(0)" ::: "memory");

        short8 a0  = *(const short8*)(pLds + m * 144 + q4 * 16);
        short8 a1  = *(const short8*)(pLds + m * 144 + 64 + q4 * 16);
        short8 v00 = *(const short8*)(vLds + m * 144 + q4 * 16);
        short8 v10 = *(const short8*)(vLds + m * 144 + 64 + q4 * 16);
        short8 v01 = *(const short8*)(vLds + (16 + m) * 144 + q4 * 16);
        short8 v11 = *(const short8*)(vLds + (16 + m) * 144 + 64 + q4 * 16);
        O0 = __builtin_amdgcn_mfma_f32_16x16x32_bf16(a0, v00, O0, 0, 0, 0);
        O0 = __builtin_amdgcn_mfma_f32_16x16x32_bf16(a1, v10, O0, 0, 0, 0);
        O1 = __builtin_amdgcn_mfma_f32_16x16x32_bf16(a0, v01, O1, 0, 0, 0);
        O1 = __builtin_amdgcn_mfma_f32_16x16x32_bf16(a1, v11, O1, 0, 0, 0);
    }

    const int b = bh >> 2, h = bh & 3;
    #pragma unroll
    for (int reg = 0; reg < 4; ++reg) {
        const float inv = 1.f / ls[reg];
        const int t = qt * 64 + wave * 16 + q4 * 4 + reg;
        float* orow = og + (((size_t)b * T_ + t) * NH_ + h) * HD_;
        orow[m]      = O0[reg] * inv;
        orow[16 + m] = O1[reg] * inv;
    }
}

// -------------------------------------------------------------------------
// Kernel 3: output projection via MFMA, hi/lo bf16 split.
// out[m,n] = sum_k attn[m,k] * Wout[n,k];  M=16384, N=128 (2 chunks), K=128.
// -------------------------------------------------------------------------
__global__ __launch_bounds__(256) void out_proj_kernel(
    const float* __restrict__ a, const float* __restrict__ Wout,
    float* __restrict__ out)
{
    __shared__ __align__(16) unsigned short lds[4 * 64 * LROW];   // 68 KB
    unsigned short* xhi = lds;
    unsigned short* xlo = lds + 64 * LROW;
    unsigned short* whi = lds + 2 * 64 * LROW;
    unsigned short* wlo = lds + 3 * 64 * LROW;

    const int tid  = threadIdx.x;
    const int wave = tid >> 6, lane = tid & 63;
    const int m    = lane & 15, q4 = lane >> 4;
    const int m0   = blockIdx.x * 64;

    {   // stage attn tile 64x128 fp32 -> hi/lo bf16 LDS
        const float4* xg = (const float4*)(a + (size_t)m0 * DM_);
        #pragma unroll
        for (int i = 0; i < 8; ++i) {
            const int f = tid + 256 * i;
            float4 v = xg[f];
            const int row = f >> 5, k4 = f & 31;
            ushort4 h, l;
            split_bf(v.x, h.x, l.x); split_bf(v.y, h.y, l.y);
            split_bf(v.z, h.z, l.z); split_bf(v.w, h.w, l.w);
            *(ushort4*)(xhi + row * LROW + k4 * 4) = h;
            *(ushort4*)(xlo + row * LROW + k4 * 4) = l;
        }
    }
    __syncthreads();

    short8 Ah[4], Al[4];
    #pragma unroll
    for (int ks = 0; ks < 4; ++ks) {
        Ah[ks] = *(const short8*)(xhi + (wave * 16 + m) * LROW + ks * 32 + q4 * 8);
        Al[ks] = *(const short8*)(xlo + (wave * 16 + m) * LROW + ks * 32 + q4 * 8);
    }

    for (int ch = 0; ch < 2; ++ch) {
        float4 wreg[8];
        {
            const float4* wg = (const float4*)(Wout + (size_t)ch * 64 * DM_);
            #pragma unroll
            for (int i = 0; i < 8; ++i) wreg[i] = wg[tid + 256 * i];
        }
        __syncthreads();
        #pragma unroll
        for (int i = 0; i < 8; ++i) {
            const int f = tid + 256 * i;
            const int row = f >> 5, k4 = f & 31;
            ushort4 h, l;
            split_bf(wreg[i].x, h.x, l.x); split_bf(wreg[i].y, h.y, l.y);
            split_bf(wreg[i].z, h.z, l.z); split_bf(wreg[i].w, h.w, l.w);
            *(ushort4*)(whi + row * LROW + k4 * 4) = h;
            *(ushort4*)(wlo + row * LROW + k4 * 4) = l;
        }
        __syncthreads();

        #pragma unroll
        for (int nb = 0; nb < 4; ++nb) {
            floatx4 acc = {0.f, 0.f, 0.f, 0.f};
            #pragma unroll
            for (int ks = 0; ks < 4; ++ks) {
                short8 Bh = *(const short8*)(whi + (nb * 16 + m) * LROW + ks * 32 + q4 * 8);
                short8 Bl = *(const short8*)(wlo + (nb * 16 + m) * LROW + ks * 32 + q4 * 8);
                acc = __builtin_amdgcn_mfma_f32_16x16x32_bf16(Ah[ks], Bh, acc, 0, 0, 0);
                acc = __builtin_amdgcn_mfma_f32_16x16x32_bf16(Ah[ks], Bl, acc, 0, 0, 0);
                acc = __builtin_amdgcn_mfma_f32_16x16x32_bf16(Al[ks], Bh, acc, 0, 0, 0);
            }
            const int n = ch * 64 + nb * 16 + m;
            #pragma unroll
            for (int reg = 0; reg < 4; ++reg) {
                const int token = m0 + wave * 16 + q4 * 4 + reg;
                out[(size_t)token * DM_ + n] = acc[reg];
            }
        }
    }
}

// -------------------------------------------------------------------------
extern "C" void kernel_launch(void* const* d_in, const int* in_sizes, int n_in,
                              void* d_out, int out_size, void* d_ws, size_t ws_size,
                              hipStream_t stream) {
    const float* x    = (const float*)d_in[0];   // (4,4096,128) fp32
    const float* Wqkv = (const float*)d_in[1];   // (384,128)    fp32
    const float* Wout = (const float*)d_in[2];   // (128,128)    fp32
    float* out = (float*)d_out;                  // (4,4096,128) fp32

    // ws layout (bytes): q_bf 4MB | k_bf 4MB | v_t 4MB | att_ws fp32 8MB
    char* ws = (char*)d_ws;
    unsigned short* q_bf  = (unsigned short*)(ws);
    unsigned short* k_bf  = (unsigned short*)(ws + (size_t)4 * 1024 * 1024);
    unsigned short* v_t   = (unsigned short*)(ws + (size_t)8 * 1024 * 1024);
    float*          att_ws = (float*)(ws + (size_t)12 * 1024 * 1024);

    qkv_proj_kernel<<<TOKENS / 64, 256, 0, stream>>>(x, Wqkv, q_bf, k_bf, v_t);
    attn_mfma_kernel<<<1024, 256, 0, stream>>>(q_bf, k_bf, v_t, att_ws);
    out_proj_kernel<<<TOKENS / 64, 256, 0, stream>>>(att_ws, Wout, out);
}

// Round 5
// 146.765 us; speedup vs baseline: 9.6291x; 1.2772x over previous
//
#include <hip/hip_runtime.h>
#include <math.h>

// Problem constants (reference: B=4, T=4096, D_MODEL=128, N_HEADS=4, HEAD_DIM=32)
#define B_   4
#define T_   4096
#define DM_  128
#define NH_  4
#define HD_  32
#define TOKENS (B_ * T_)               // 16384

typedef __attribute__((ext_vector_type(8))) short short8;   // 8 bf16 = 4 VGPRs (MFMA A/B frag)
typedef __attribute__((ext_vector_type(4))) float floatx4;  // MFMA C/D frag

__device__ __forceinline__ unsigned short f2bf(float f) {
    union { float f; unsigned int u; } v; v.f = f;
    unsigned int u = v.u;
    u += 0x7fffu + ((u >> 16) & 1u);   // round-to-nearest-even
    return (unsigned short)(u >> 16);
}
__device__ __forceinline__ void split_bf(float v, unsigned short& hi, unsigned short& lo) {
    unsigned short h = f2bf(v);
    float hf = __uint_as_float(((unsigned int)h) << 16);
    hi = h;
    lo = f2bf(v - hf);
}

// LDS row stride for bf16 W tiles: 128 elements + 8 pad = 136 shorts = 272 B.
#define LROW 136

// -------------------------------------------------------------------------
// Kernel 1: QKV projection via MFMA, hi/lo bf16 split.
// grid (M/64, 6): blockIdx.y = 64-col chunk of N=384.  A-frags direct from
// global (no x LDS); W chunk cooperatively hi/lo split into LDS.
// Outputs: Q bf16 (bh,t,32) PRE-SCALED by log2(e)/sqrt(32) [exp2-domain];
//          K bf16 (bh,t,32); V^T bf16 (bh,32,t).
// -------------------------------------------------------------------------
__global__ __launch_bounds__(256) void qkv_proj_kernel(
    const float* __restrict__ x, const float* __restrict__ Wqkv,
    unsigned short* __restrict__ q_bf, unsigned short* __restrict__ k_bf,
    unsigned short* __restrict__ v_t)
{
    __shared__ __align__(16) unsigned short whi[64 * LROW];   // 17 KB
    __shared__ __align__(16) unsigned short wlo[64 * LROW];   // 17 KB

    const int tid  = threadIdx.x;
    const int wave = tid >> 6, lane = tid & 63;
    const int m    = lane & 15, q4 = lane >> 4;
    const int m0   = blockIdx.x * 64;
    const int ch   = blockIdx.y;                  // 0..5
    const float scale = 0.2550052509571414f;      // log2(e)/sqrt(32)

    {   // cooperative W chunk split: rows ch*64 .. +63
        const float4* wg = (const float4*)(Wqkv + (size_t)ch * 64 * DM_);
        #pragma unroll
        for (int i = 0; i < 8; ++i) {
            const int f = tid + 256 * i;
            float4 v = wg[f];
            const int row = f >> 5, k4 = f & 31;
            ushort4 h, l;
            split_bf(v.x, h.x, l.x); split_bf(v.y, h.y, l.y);
            split_bf(v.z, h.z, l.z); split_bf(v.w, h.w, l.w);
            *(ushort4*)(whi + row * LROW + k4 * 4) = h;
            *(ushort4*)(wlo + row * LROW + k4 * 4) = l;
        }
    }

    // A-frags direct from global: row m0+wave*16+m, cols ks*32+q4*8..+7
    short8 Ah[4], Al[4];
    {
        const float4* xg = (const float4*)(x + (size_t)(m0 + wave * 16 + m) * DM_);
        #pragma unroll
        for (int ks = 0; ks < 4; ++ks) {
            float4 a = xg[ks * 8 + q4 * 2];
            float4 b = xg[ks * 8 + q4 * 2 + 1];
            ushort4 h0, l0, h1, l1;
            split_bf(a.x, h0.x, l0.x); split_bf(a.y, h0.y, l0.y);
            split_bf(a.z, h0.z, l0.z); split_bf(a.w, h0.w, l0.w);
            split_bf(b.x, h1.x, l1.x); split_bf(b.y, h1.y, l1.y);
            split_bf(b.z, h1.z, l1.z); split_bf(b.w, h1.w, l1.w);
            Ah[ks] = short8{(short)h0.x, (short)h0.y, (short)h0.z, (short)h0.w,
                            (short)h1.x, (short)h1.y, (short)h1.z, (short)h1.w};
            Al[ks] = short8{(short)l0.x, (short)l0.y, (short)l0.z, (short)l0.w,
                            (short)l1.x, (short)l1.y, (short)l1.z, (short)l1.w};
        }
    }
    __syncthreads();

    #pragma unroll
    for (int nb = 0; nb < 4; ++nb) {
        floatx4 acc = {0.f, 0.f, 0.f, 0.f};
        #pragma unroll
        for (int ks = 0; ks < 4; ++ks) {
            short8 Bh = *(const short8*)(whi + (nb * 16 + m) * LROW + ks * 32 + q4 * 8);
            short8 Bl = *(const short8*)(wlo + (nb * 16 + m) * LROW + ks * 32 + q4 * 8);
            acc = __builtin_amdgcn_mfma_f32_16x16x32_bf16(Ah[ks], Bh, acc, 0, 0, 0);
            acc = __builtin_amdgcn_mfma_f32_16x16x32_bf16(Ah[ks], Bl, acc, 0, 0, 0);
            acc = __builtin_amdgcn_mfma_f32_16x16x32_bf16(Al[ks], Bh, acc, 0, 0, 0);
        }
        // n = ch*64 + nb*16 + m ; cidx=n>>7 (0=q,1=k,2=v), h=(n>>5)&3, d=n&31
        const int n    = ch * 64 + nb * 16 + m;
        const int cidx = n >> 7;
        const int hh   = (n >> 5) & 3;
        const int d    = n & 31;
        const int tok0 = m0 + wave * 16 + q4 * 4;      // token for reg 0
        const int b    = tok0 >> 12;
        const int t0   = tok0 & (T_ - 1);
        const int bh   = b * NH_ + hh;
        if (cidx == 0) {
            #pragma unroll
            for (int reg = 0; reg < 4; ++reg)
                q_bf[((size_t)bh * T_ + t0 + reg) * HD_ + d] = f2bf(acc[reg] * scale);
        } else if (cidx == 1) {
            #pragma unroll
            for (int reg = 0; reg < 4; ++reg)
                k_bf[((size_t)bh * T_ + t0 + reg) * HD_ + d] = f2bf(acc[reg]);
        } else {
            ushort4 p;
            p.x = f2bf(acc[0]); p.y = f2bf(acc[1]);
            p.z = f2bf(acc[2]); p.w = f2bf(acc[3]);
            *(ushort4*)(v_t + ((size_t)bh * HD_ + d) * T_ + t0) = p;
        }
    }
}

// -------------------------------------------------------------------------
// Kernel 2: bf16 MFMA causal flash attention, S-TRANSPOSED formulation.
// S^T = K·Q^T  ->  C col = query row (one query per lane: scalar stats,
// 2-shuffle reductions).  P^T packed in-register (v_perm) -> 4 ds_write_b64
// -> read back as PV B-frags.  O^T = V^T·P^T.  exp2-domain softmax.
// -------------------------------------------------------------------------
__global__ __launch_bounds__(256, 4) void attn_mfma_kernel(
    const unsigned short* __restrict__ qb, const unsigned short* __restrict__ kb,
    const unsigned short* __restrict__ vtb, float* __restrict__ og)
{
    __shared__ __align__(16) char smem[5120 + 4608 + 4 * 2304];   // 18.5 KB
    char* kLds = smem;             // 64 rows x 80 B  (K tile, (t,d))
    char* vLds = smem + 5120;      // 32 rows x 144 B (V^T tile, (d,t))
    const int tid  = threadIdx.x;
    const int wave = tid >> 6, lane = tid & 63;
    const int m    = lane & 15, q4 = lane >> 4;
    char* pT = smem + 9728 + wave * 2304;   // wave-private P^T: 16 q-rows x 144 B

    // Dispatch swizzle: XCD-locality (2 heads per XCD) + per-CU qt balance.
    const int pid = blockIdx.x;
    const int xcd = pid & 7;
    const int r_  = pid >> 3;
    const int bh  = xcd * 2 + (r_ & 1);
    const int j_  = r_ >> 1;
    const int a_  = j_ & 15, k_ = j_ >> 4;
    const int qt  = (k_ == 0) ? a_ : (k_ == 1) ? 63 - a_
                  : (k_ == 2) ? 32 + a_ : 31 - a_;

    const size_t qkbase = (size_t)bh * T_ * HD_;
    const char* kg = (const char*)(kb + qkbase);
    const char* vg = (const char*)(vtb + qkbase);

    // Q B-fragment: row qt*64+wave*16+m, k-bytes q4*16 (Q pre-scaled, exp2 domain)
    short8 qf = *(const short8*)((const char*)(qb + qkbase)
                 + (size_t)(qt * 64 + wave * 16 + m) * 64 + q4 * 16);
    const int qrow = wave * 16 + m;        // query row within the 64-block

    floatx4 O0 = {0.f, 0.f, 0.f, 0.f}, O1 = {0.f, 0.f, 0.f, 0.f};
    float mx = -INFINITY, ls = 0.f;

    for (int kt = 0; kt <= qt; ++kt) {
        __syncthreads();
        {   // stage K tile (64x64B) + V^T tile (32x128B), split over 256 thr
            const int krow = tid >> 2, ku = tid & 3;
            short8 kv = *(const short8*)(kg + (size_t)(kt * 64 + krow) * 64 + ku * 16);
            const int vd = tid >> 3, vu = tid & 7;
            short8 vv = *(const short8*)(vg + (size_t)vd * (T_ * 2)
                                            + (size_t)kt * 128 + vu * 16);
            *(short8*)(kLds + krow * 80 + ku * 16) = kv;
            *(short8*)(vLds + vd * 144 + vu * 16) = vv;
        }
        __syncthreads();

        // S^T = K·Q^T : A = K rows (s), B = Q rows (q).  C[s=q4*4+reg][q=m]
        floatx4 st[4];
        #pragma unroll
        for (int sb = 0; sb < 4; ++sb) {
            short8 kfrag = *(const short8*)(kLds + (sb * 16 + m) * 80 + q4 * 16);
            floatx4 z = {0.f, 0.f, 0.f, 0.f};
            st[sb] = __builtin_amdgcn_mfma_f32_16x16x32_bf16(kfrag, qf, z, 0, 0, 0);
        }

        if (kt == qt) {   // causal: mask s_local > qrow
            #pragma unroll
            for (int sb = 0; sb < 4; ++sb)
                #pragma unroll
                for (int reg = 0; reg < 4; ++reg)
                    if (sb * 16 + q4 * 4 + reg > qrow) st[sb][reg] = -INFINITY;
        }

        // per-lane row stats over 16 s-values + 2 cross-quad shuffles
        float rmax = -INFINITY;
        #pragma unroll
        for (int sb = 0; sb < 4; ++sb)
            #pragma unroll
            for (int reg = 0; reg < 4; ++reg) rmax = fmaxf(rmax, st[sb][reg]);
        rmax = fmaxf(rmax, __shfl_xor(rmax, 16, 64));
        rmax = fmaxf(rmax, __shfl_xor(rmax, 32, 64));

        const float mn = fmaxf(mx, rmax);
        const float alpha = __builtin_amdgcn_exp2f(mx - mn);   // exp2(-inf)=0 first tile
        mx = mn;

        // p = exp2(s - mn); pack hi16 (round-half-up) via v_perm; 4 b64 writes
        float psum = 0.f;
        #pragma unroll
        for (int sb = 0; sb < 4; ++sb) {
            float p0 = __builtin_amdgcn_exp2f(st[sb][0] - mn);
            float p1 = __builtin_amdgcn_exp2f(st[sb][1] - mn);
            float p2 = __builtin_amdgcn_exp2f(st[sb][2] - mn);
            float p3 = __builtin_amdgcn_exp2f(st[sb][3] - mn);
            psum += (p0 + p1) + (p2 + p3);
            unsigned u0 = __float_as_uint(p0) + 0x8000u;
            unsigned u1 = __float_as_uint(p1) + 0x8000u;
            unsigned u2 = __float_as_uint(p2) + 0x8000u;
            unsigned u3 = __float_as_uint(p3) + 0x8000u;
            uint2 pk;
            pk.x = __builtin_amdgcn_perm(u1, u0, 0x07060302);  // [bf(p0) | bf(p1)<<16]
            pk.y = __builtin_amdgcn_perm(u3, u2, 0x07060302);
            *(uint2*)(pT + m * 144 + sb * 32 + q4 * 8) = pk;   // P^T[q=m][s=sb*16+q4*4..+3]
        }
        psum += __shfl_xor(psum, 16, 64);
        psum += __shfl_xor(psum, 32, 64);
        ls = ls * alpha + psum;
        #pragma unroll
        for (int reg = 0; reg < 4; ++reg) { O0[reg] *= alpha; O1[reg] *= alpha; }

        // drain wave-internal P^T writes before cross-lane B-frag reads
        __asm__ volatile("s_waitcnt lgkmcnt(0)" ::: "memory");

        // O^T += V^T · P^T : A = V^T rows (d), B = P^T rows (q)
        short8 b0  = *(const short8*)(pT + m * 144 + q4 * 16);        // s 0..31
        short8 b1  = *(const short8*)(pT + m * 144 + 64 + q4 * 16);   // s 32..63
        short8 v00 = *(const short8*)(vLds + m * 144 + q4 * 16);
        short8 v10 = *(const short8*)(vLds + m * 144 + 64 + q4 * 16);
        short8 v01 = *(const short8*)(vLds + (16 + m) * 144 + q4 * 16);
        short8 v11 = *(const short8*)(vLds + (16 + m) * 144 + 64 + q4 * 16);
        O0 = __builtin_amdgcn_mfma_f32_16x16x32_bf16(v00, b0, O0, 0, 0, 0);
        O0 = __builtin_amdgcn_mfma_f32_16x16x32_bf16(v10, b1, O0, 0, 0, 0);
        O1 = __builtin_amdgcn_mfma_f32_16x16x32_bf16(v01, b0, O1, 0, 0, 0);
        O1 = __builtin_amdgcn_mfma_f32_16x16x32_bf16(v11, b1, O1, 0, 0, 0);
    }

    // epilogue: O^T[d][q=m] -> lane holds d = q4*4+reg (+16);  t = per-lane row
    const float inv = 1.f / ls;
    const int b = bh >> 2, h = bh & 3;
    const int t = qt * 64 + qrow;
    float* orow = og + (((size_t)b * T_ + t) * NH_ + h) * HD_;
    *(float4*)(orow + q4 * 4)      = make_float4(O0[0] * inv, O0[1] * inv,
                                                 O0[2] * inv, O0[3] * inv);
    *(float4*)(orow + 16 + q4 * 4) = make_float4(O1[0] * inv, O1[1] * inv,
                                                 O1[2] * inv, O1[3] * inv);
}

// -------------------------------------------------------------------------
// Kernel 3: output projection via MFMA, hi/lo bf16 split.
// grid (M/64, 2): blockIdx.y = 64-col chunk of N=128.  A-frags direct from
// global; Wout chunk cooperatively split into LDS.
// -------------------------------------------------------------------------
__global__ __launch_bounds__(256) void out_proj_kernel(
    const float* __restrict__ a, const float* __restrict__ Wout,
    float* __restrict__ out)
{
    __shared__ __align__(16) unsigned short whi[64 * LROW];
    __shared__ __align__(16) unsigned short wlo[64 * LROW];

    const int tid  = threadIdx.x;
    const int wave = tid >> 6, lane = tid & 63;
    const int m    = lane & 15, q4 = lane >> 4;
    const int m0   = blockIdx.x * 64;
    const int ch   = blockIdx.y;                  // 0..1

    {   // cooperative W chunk split
        const float4* wg = (const float4*)(Wout + (size_t)ch * 64 * DM_);
        #pragma unroll
        for (int i = 0; i < 8; ++i) {
            const int f = tid + 256 * i;
            float4 v = wg[f];
            const int row = f >> 5, k4 = f & 31;
            ushort4 h, l;
            split_bf(v.x, h.x, l.x); split_bf(v.y, h.y, l.y);
            split_bf(v.z, h.z, l.z); split_bf(v.w, h.w, l.w);
            *(ushort4*)(whi + row * LROW + k4 * 4) = h;
            *(ushort4*)(wlo + row * LROW + k4 * 4) = l;
        }
    }

    short8 Ah[4], Al[4];
    {
        const float4* xg = (const float4*)(a + (size_t)(m0 + wave * 16 + m) * DM_);
        #pragma unroll
        for (int ks = 0; ks < 4; ++ks) {
            float4 av = xg[ks * 8 + q4 * 2];
            float4 bv = xg[ks * 8 + q4 * 2 + 1];
            ushort4 h0, l0, h1, l1;
            split_bf(av.x, h0.x, l0.x); split_bf(av.y, h0.y, l0.y);
            split_bf(av.z, h0.z, l0.z); split_bf(av.w, h0.w, l0.w);
            split_bf(bv.x, h1.x, l1.x); split_bf(bv.y, h1.y, l1.y);
            split_bf(bv.z, h1.z, l1.z); split_bf(bv.w, h1.w, l1.w);
            Ah[ks] = short8{(short)h0.x, (short)h0.y, (short)h0.z, (short)h0.w,
                            (short)h1.x, (short)h1.y, (short)h1.z, (short)h1.w};
            Al[ks] = short8{(short)l0.x, (short)l0.y, (short)l0.z, (short)l0.w,
                            (short)l1.x, (short)l1.y, (short)l1.z, (short)l1.w};
        }
    }
    __syncthreads();

    #pragma unroll
    for (int nb = 0; nb < 4; ++nb) {
        floatx4 acc = {0.f, 0.f, 0.f, 0.f};
        #pragma unroll
        for (int ks = 0; ks < 4; ++ks) {
            short8 Bh = *(const short8*)(whi + (nb * 16 + m) * LROW + ks * 32 + q4 * 8);
            short8 Bl = *(const short8*)(wlo + (nb * 16 + m) * LROW + ks * 32 + q4 * 8);
            acc = __builtin_amdgcn_mfma_f32_16x16x32_bf16(Ah[ks], Bh, acc, 0, 0, 0);
            acc = __builtin_amdgcn_mfma_f32_16x16x32_bf16(Ah[ks], Bl, acc, 0, 0, 0);
            acc = __builtin_amdgcn_mfma_f32_16x16x32_bf16(Al[ks], Bh, acc, 0, 0, 0);
        }
        const int n = ch * 64 + nb * 16 + m;
        const int tok0 = m0 + wave * 16 + q4 * 4;
        #pragma unroll
        for (int reg = 0; reg < 4; ++reg)
            out[(size_t)(tok0 + reg) * DM_ + n] = acc[reg];
    }
}

// -------------------------------------------------------------------------
extern "C" void kernel_launch(void* const* d_in, const int* in_sizes, int n_in,
                              void* d_out, int out_size, void* d_ws, size_t ws_size,
                              hipStream_t stream) {
    const float* x    = (const float*)d_in[0];   // (4,4096,128) fp32
    const float* Wqkv = (const float*)d_in[1];   // (384,128)    fp32
    const float* Wout = (const float*)d_in[2];   // (128,128)    fp32
    float* out = (float*)d_out;                  // (4,4096,128) fp32

    // ws layout (bytes): q_bf 4MB | k_bf 4MB | v_t 4MB | att_ws fp32 8MB
    char* ws = (char*)d_ws;
    unsigned short* q_bf  = (unsigned short*)(ws);
    unsigned short* k_bf  = (unsigned short*)(ws + (size_t)4 * 1024 * 1024);
    unsigned short* v_t   = (unsigned short*)(ws + (size_t)8 * 1024 * 1024);
    float*          att_ws = (float*)(ws + (size_t)12 * 1024 * 1024);

    qkv_proj_kernel<<<dim3(TOKENS / 64, 6), 256, 0, stream>>>(x, Wqkv, q_bf, k_bf, v_t);
    attn_mfma_kernel<<<1024, 256, 0, stream>>>(q_bf, k_bf, v_t, att_ws);
    out_proj_kernel<<<dim3(TOKENS / 64, 2), 256, 0, stream>>>(att_ws, Wout, out);
}